// Round 2
// baseline (327.023 us; speedup 1.0000x reference)
//
#include <hip/hip_runtime.h>

#define HID 2048
#define NEXP 64
#define NTOK 16384
#define TM 32            // tokens per block (one 32-row MFMA tile)
#define NTHREADS 512     // 8 waves
#define KPH 8            // K-phases = waves per block
#define CPW 4            // chunks per wave (32 / KPH)
#define TPW 4            // tokens per wave in epilogue (TM / KPH)
#define NBLK (NTOK / TM) // 512
#define WS_W_OFF 1024    // W planes start here in d_ws
#define CHUNK_B 24576    // 4 ksteps * 3 planes * 2 halves * 1024 B

// out layout (f32): weights [0,32768) | indices [32768,65536) | aux 65536 | counts [65537,65601)
#define OUT_IDX_OFF (2 * NTOK)
#define OUT_AUX_OFF (4 * NTOK)
#define OUT_CNT_OFF (4 * NTOK + 1)

typedef __attribute__((ext_vector_type(8))) short bhalf8;    // 8 bf16 = 4 VGPRs (A/B frag)
typedef __attribute__((ext_vector_type(16))) float f32x16;   // 32x32 C/D frag

// async 1KB global->LDS stage: per-lane 16B source, LDS dest = base + lane*16
__device__ __forceinline__ void stage1k(const void* g, void* l) {
    __builtin_amdgcn_global_load_lds((const __attribute__((address_space(1))) void*)g,
                                     (__attribute__((address_space(3))) void*)l, 16, 0, 0);
}

// Exact 3-way RNE bf16 split (for W, precomputed): v == h1+h2+h3 exactly.
__device__ __forceinline__ void split3(float v, unsigned short& h1, unsigned short& h2, unsigned short& h3) {
    unsigned int u = __float_as_uint(v);
    unsigned int r1 = (u + 0x7FFFu + ((u >> 16) & 1u)) & 0xFFFF0000u;
    float f1 = __uint_as_float(r1);
    float d1 = v - f1;
    unsigned int u2 = __float_as_uint(d1);
    unsigned int r2 = (u2 + 0x7FFFu + ((u2 >> 16) & 1u)) & 0xFFFF0000u;
    float f2 = __uint_as_float(r2);
    float d2 = d1 - f2;
    h1 = (unsigned short)(r1 >> 16);
    h2 = (unsigned short)(r2 >> 16);
    h3 = (unsigned short)(__float_as_uint(d2) >> 16);
}

// Truncating 3-plane split of 8 fp32 -> three bf16x8 A-frags, in registers.
__device__ __forceinline__ void xsplit(float4 va, float4 vb, bhalf8& o1, bhalf8& o2, bhalf8& o3) {
    float f[8] = {va.x, va.y, va.z, va.w, vb.x, vb.y, vb.z, vb.w};
    union U { bhalf8 v; unsigned int u[4]; } u1, u2, u3;
#pragma unroll
    for (int t = 0; t < 4; t++) {
        float a = f[2 * t], b = f[2 * t + 1];
        unsigned int ua = __float_as_uint(a), ub = __float_as_uint(b);
        float da = a - __uint_as_float(ua & 0xFFFF0000u);
        float db = b - __uint_as_float(ub & 0xFFFF0000u);
        unsigned int uda = __float_as_uint(da), udb = __float_as_uint(db);
        float da2 = da - __uint_as_float(uda & 0xFFFF0000u);
        float db2 = db - __uint_as_float(udb & 0xFFFF0000u);
        u1.u[t] = (ua >> 16) | (ub & 0xFFFF0000u);
        u2.u[t] = (uda >> 16) | (udb & 0xFFFF0000u);
        u3.u[t] = (__float_as_uint(da2) >> 16) | (__float_as_uint(db2) & 0xFFFF0000u);
    }
    o1 = u1.v; o2 = u2.v; o3 = u3.v;
}

// ---- pre-kernel: split W into 3 bf16 planes in coalesced B-fragment layout ----
__global__ __launch_bounds__(64) void wsplit_kernel(const float* __restrict__ W,
                                                    char* __restrict__ wq,
                                                    float* __restrict__ wsf) {
    if (blockIdx.x < 3) wsf[blockIdx.x * 64 + threadIdx.x] = 0.f;   // zero accum[0,192): probs,counts,counter
    int idx8 = (blockIdx.x * 64 + threadIdx.x) * 8;   // 16384 threads x 8 elems
    int e = idx8 >> 11;
    int k0 = idx8 & 2047;                // octet-aligned k
    int c = k0 >> 6, ks = (k0 >> 4) & 3, half = (k0 >> 3) & 1;
    int g = e >> 5, l = (e & 31) + 32 * half;
    const float4* wp = (const float4*)(W + (size_t)e * HID + k0);
    float4 v0 = wp[0], v1 = wp[1];
    float f[8] = {v0.x, v0.y, v0.z, v0.w, v1.x, v1.y, v1.z, v1.w};
    unsigned int p1[4], p2[4], p3[4];
#pragma unroll
    for (int t = 0; t < 4; t++) {
        unsigned short a1, a2, a3, b1, b2, b3;
        split3(f[2 * t], a1, a2, a3);
        split3(f[2 * t + 1], b1, b2, b3);
        p1[t] = (unsigned int)a1 | ((unsigned int)b1 << 16);
        p2[t] = (unsigned int)a2 | ((unsigned int)b2 << 16);
        p3[t] = (unsigned int)a3 | ((unsigned int)b3 << 16);
    }
    char* base = wq + (size_t)(((c * 4 + ks) * 3 + 0) * 2 + g) * 1024 + l * 16;
    *(uint4*)(base)        = make_uint4(p1[0], p1[1], p1[2], p1[3]);   // plane 1
    *(uint4*)(base + 2048) = make_uint4(p2[0], p2[1], p2[2], p2[3]);   // plane 2
    *(uint4*)(base + 4096) = make_uint4(p3[0], p3[1], p3[2], p3[3]);   // plane 3
}

__global__ __launch_bounds__(NTHREADS, 4) void router_main(
    const float* __restrict__ x, const char* __restrict__ wq,
    float* __restrict__ out, float* __restrict__ wsf)
{
    // per-wave x staging: 2 x 4KB half-chunk buffers (32 rows x 128B, XOR-swizzled rows)
    __shared__ __align__(16) char xs[KPH * 8192];      // 64 KB
    __shared__ float slab[TM * 68];                    // 8.7 KB accumulated logits
    __shared__ float scount[NEXP];
    __shared__ float sprob[NEXP];
    __shared__ int slast;

    const int tid = threadIdx.x;
    const int w = tid >> 6;        // kphase / wave id
    const int lane = tid & 63;
    const int r = lane & 31;       // A row (token) / B expert within group
    const int h = lane >> 5;       // k-octet half
    const int n0 = blockIdx.x * TM;

    // zero logit accumulator + stats
    for (int i = tid; i < TM * 68; i += NTHREADS) slab[i] = 0.f;
    if (tid < NEXP) { scount[tid] = 0.f; sprob[tid] = 0.f; }
    __syncthreads();

    // ---- per-lane staging geometry ----
    // stage call q moves rows q*8+rl; lane's 16B slot sl; source pre-swizzled so that
    // LDS[row*128 + s*16] holds x[row][ (s*16) ^ ((row&7)<<4) ]  (rule #21 both-sides)
    const int rl = lane >> 3, sl = lane & 7;
    const char* gb = (const char*)x + (size_t)(n0 + rl) * (HID * 4) + ((sl * 16) ^ (rl << 4));
    char* xw = xs + w * 8192;
    const int swz = (r & 7) << 4;

    f32x16 acc0, acc1;
#pragma unroll
    for (int i = 0; i < 16; i++) { acc0[i] = 0.f; acc1[i] = 0.f; }

    const char* wcb = wq + (size_t)(w * CPW) * CHUNK_B + lane * 16;

    // prologue: stage half-step 0 (chunk w*CPW, low half) into buf0
    {
        const char* g0 = gb + (size_t)(w * CPW) * 256;
#pragma unroll
        for (int q = 0; q < 4; q++)
            stage1k(g0 + q * 65536, xw + q * 1024);
    }

    // ---- free-running K-loop over 8 half-steps (4 chunks x 2 halves), no barriers ----
#pragma unroll 1
    for (int t = 0; t < 2 * CPW; ++t) {
        const char* wk0 = wcb + (size_t)(t >> 1) * CHUNK_B + (t & 1) * 12288;
        // batch this half's 12 wq B-frags (oldest in vmcnt queue)
        bhalf8 Bf[2][6];
#pragma unroll
        for (int ksl = 0; ksl < 2; ksl++)
#pragma unroll
            for (int p5 = 0; p5 < 6; p5++)
                Bf[ksl][p5] = *(const bhalf8*)(wk0 + ksl * 6144 + p5 * 1024);

        if (t < 2 * CPW - 1) {
            // issue next half's 4 async stage loads (newest 4 in vmcnt queue)
            const int tn = t + 1;
            const char* gn = gb + (size_t)(w * CPW + (tn >> 1)) * 256 + (tn & 1) * 128;
            char* ln = xw + (tn & 1) * 4096;
#pragma unroll
            for (int q = 0; q < 4; q++)
                stage1k(gn + q * 65536, ln + q * 1024);
            __builtin_amdgcn_sched_barrier(0);
            asm volatile("s_waitcnt vmcnt(4)" ::: "memory");   // current stage + wq drained; next stage in flight
            __builtin_amdgcn_sched_barrier(0);
        } else {
            __builtin_amdgcn_sched_barrier(0);
            asm volatile("s_waitcnt vmcnt(0)" ::: "memory");
            __builtin_amdgcn_sched_barrier(0);
        }

        const char* xb = xw + (t & 1) * 4096;
#pragma unroll
        for (int ksl = 0; ksl < 2; ksl++) {
            // A-frag from staged LDS (swizzled read matches pre-swizzled source)
            float4 pva = *(const float4*)(xb + r * 128 + ((ksl * 64 + h * 32) ^ swz));
            float4 pvb = *(const float4*)(xb + r * 128 + ((ksl * 64 + h * 32 + 16) ^ swz));
            bhalf8 A1, A2, A3;
            xsplit(pva, pvb, A1, A2, A3);
            acc0 = __builtin_amdgcn_mfma_f32_32x32x16_bf16(A1, Bf[ksl][0], acc0, 0, 0, 0);
            acc0 = __builtin_amdgcn_mfma_f32_32x32x16_bf16(A1, Bf[ksl][2], acc0, 0, 0, 0);
            acc0 = __builtin_amdgcn_mfma_f32_32x32x16_bf16(A2, Bf[ksl][0], acc0, 0, 0, 0);
            acc0 = __builtin_amdgcn_mfma_f32_32x32x16_bf16(A1, Bf[ksl][4], acc0, 0, 0, 0);
            acc0 = __builtin_amdgcn_mfma_f32_32x32x16_bf16(A2, Bf[ksl][2], acc0, 0, 0, 0);
            acc0 = __builtin_amdgcn_mfma_f32_32x32x16_bf16(A3, Bf[ksl][0], acc0, 0, 0, 0);
            acc1 = __builtin_amdgcn_mfma_f32_32x32x16_bf16(A1, Bf[ksl][1], acc1, 0, 0, 0);
            acc1 = __builtin_amdgcn_mfma_f32_32x32x16_bf16(A1, Bf[ksl][3], acc1, 0, 0, 0);
            acc1 = __builtin_amdgcn_mfma_f32_32x32x16_bf16(A2, Bf[ksl][1], acc1, 0, 0, 0);
            acc1 = __builtin_amdgcn_mfma_f32_32x32x16_bf16(A1, Bf[ksl][5], acc1, 0, 0, 0);
            acc1 = __builtin_amdgcn_mfma_f32_32x32x16_bf16(A2, Bf[ksl][3], acc1, 0, 0, 0);
            acc1 = __builtin_amdgcn_mfma_f32_32x32x16_bf16(A3, Bf[ksl][1], acc1, 0, 0, 0);
        }
    }

    // ---- combine: accumulate partial tiles directly via LDS atomics (ds_add_f32) ----
    // C/D 32x32 layout: col = lane&31, row = (reg&3) + 8*(reg>>2) + 4*(lane>>5)  [m74/m101]
#pragma unroll
    for (int reg = 0; reg < 16; reg++) {
        int row = (reg & 3) + 8 * (reg >> 2) + 4 * h;
        atomicAdd(&slab[row * 68 + r],      acc0[reg]);
        atomicAdd(&slab[row * 68 + 32 + r], acc1[reg]);
    }
    __syncthreads();

    // ---- wave-parallel epilogue: wave w handles tokens w*TPW .. w*TPW+3 ----
    const float* logits = slab;
    float pacc = 0.f;   // per-lane (expert=lane) softmax-prob sum over this wave's tokens
#pragma unroll 1
    for (int j = 0; j < TPW; j++) {
        const int t = w * TPW + j;
        const float v = logits[t * 68 + lane];
        float m1 = v, m2 = -3.4e38f;
        int i1 = lane, i2 = 0;
#pragma unroll
        for (int off = 32; off > 0; off >>= 1) {
            float om1 = __shfl_xor(m1, off);
            int   oi1 = __shfl_xor(i1, off);
            float om2 = __shfl_xor(m2, off);
            int   oi2 = __shfl_xor(i2, off);
            if (om1 > m1 || (om1 == m1 && oi1 < i1)) {
                if (m1 > om2 || (m1 == om2 && i1 < oi2)) { m2 = m1; i2 = i1; }
                else { m2 = om2; i2 = oi2; }
                m1 = om1; i1 = oi1;
            } else {
                if (om1 > m2 || (om1 == m2 && oi1 < i2)) { m2 = om1; i2 = oi1; }
            }
        }
        float p = __expf(v - m1);
        float Z = p;
#pragma unroll
        for (int off = 32; off > 0; off >>= 1) Z += __shfl_xor(Z, off);
        float invZ = 1.f / Z;
        pacc += p * invZ;
        if (lane == 0) {
            float p1 = invZ;
            float p2 = __expf(m2 - m1) * invZ;
            float denom = p1 + p2 + 1e-6f;
            int n = n0 + t;
            out[2 * n + 0] = p1 / denom;
            out[2 * n + 1] = p2 / denom;
            out[OUT_IDX_OFF + 2 * n + 0] = (float)i1;
            out[OUT_IDX_OFF + 2 * n + 1] = (float)i2;
            atomicAdd(&scount[i1], 1.f);
            atomicAdd(&scount[i2], 1.f);
        }
    }
    atomicAdd(&sprob[lane], pacc);
    __syncthreads();

    if (tid < NEXP) {
        atomicAdd(&wsf[tid], sprob[tid]);
        atomicAdd(&wsf[NEXP + tid], scount[tid]);
    }

    // ---- last block computes aux loss + counts (folds router_finish) ----
    __threadfence();
    if (tid == 0) {
        unsigned prev = __hip_atomic_fetch_add((unsigned int*)(wsf + 2 * NEXP), 1u,
                                               __ATOMIC_ACQ_REL, __HIP_MEMORY_SCOPE_AGENT);
        slast = (prev == NBLK - 1) ? 1 : 0;
    }
    __syncthreads();
    if (slast && tid < NEXP) {
        const int e = tid;
        const float invN = 1.f / (float)NTOK;
        float ps = __hip_atomic_load(wsf + e, __ATOMIC_RELAXED, __HIP_MEMORY_SCOPE_AGENT);
        float cs = __hip_atomic_load(wsf + NEXP + e, __ATOMIC_RELAXED, __HIP_MEMORY_SCOPE_AGENT);
        out[OUT_CNT_OFF + e] = cs;
        float p = ps * invN;
        float a = cs * invN;
        float v = p * p + a * a;
#pragma unroll
        for (int off = 32; off > 0; off >>= 1)
            v += __shfl_down(v, off);
        if (e == 0) out[OUT_AUX_OFF] = v * (float)NEXP;
    }
}

extern "C" void kernel_launch(void* const* d_in, const int* in_sizes, int n_in,
                              void* d_out, int out_size, void* d_ws, size_t ws_size,
                              hipStream_t stream)
{
    const float* x = (const float*)d_in[0];   // [4,4096,2048] f32
    const float* W = (const float*)d_in[1];   // [64,2048] f32
    float* out = (float*)d_out;
    float* wsf = (float*)d_ws;
    char* wq = (char*)d_ws + WS_W_OFF;        // W planes: 32 chunks x 24576 B = 768 KB

    wsplit_kernel<<<256, 64, 0, stream>>>(W, wq, wsf);   // also zeros accum+counter
    router_main<<<NBLK, NTHREADS, 0, stream>>>(x, wq, out, wsf);
}

// Round 3
// 294.739 us; speedup vs baseline: 1.1095x; 1.1095x over previous
//
#include <hip/hip_runtime.h>

#define HID 2048
#define NEXP 64
#define NTOK 16384
#define TM 64            // tokens per block: two 32-row MFMA tiles sharing B-frags
#define NTHREADS 512     // 8 waves
#define KPH 8            // K-phases = waves per block
#define CPW 4            // chunks per wave (32 / KPH)
#define TPW 8            // tokens per wave in epilogue (TM / KPH)
#define NBLK (NTOK / TM) // 256
#define WS_W_OFF 1024    // W planes start here in d_ws
#define CHUNK_B 24576    // 4 ksteps * 3 planes * 2 halves * 1024 B

// out layout (f32): weights [0,32768) | indices [32768,65536) | aux 65536 | counts [65537,65601)
#define OUT_IDX_OFF (2 * NTOK)
#define OUT_AUX_OFF (4 * NTOK)
#define OUT_CNT_OFF (4 * NTOK + 1)

typedef __attribute__((ext_vector_type(8))) short bhalf8;    // 8 bf16 = 4 VGPRs (A/B frag)
typedef __attribute__((ext_vector_type(16))) float f32x16;   // 32x32 C/D frag

// Exact 3-way RNE bf16 split (for W, precomputed): v == h1+h2+h3 exactly.
__device__ __forceinline__ void split3(float v, unsigned short& h1, unsigned short& h2, unsigned short& h3) {
    unsigned int u = __float_as_uint(v);
    unsigned int r1 = (u + 0x7FFFu + ((u >> 16) & 1u)) & 0xFFFF0000u;
    float f1 = __uint_as_float(r1);
    float d1 = v - f1;
    unsigned int u2 = __float_as_uint(d1);
    unsigned int r2 = (u2 + 0x7FFFu + ((u2 >> 16) & 1u)) & 0xFFFF0000u;
    float f2 = __uint_as_float(r2);
    float d2 = d1 - f2;
    h1 = (unsigned short)(r1 >> 16);
    h2 = (unsigned short)(r2 >> 16);
    h3 = (unsigned short)(__float_as_uint(d2) >> 16);
}

// Truncating 3-plane split of 8 fp32 -> three bf16x8 A-frags, in registers.
__device__ __forceinline__ void xsplit(float4 va, float4 vb, bhalf8& o1, bhalf8& o2, bhalf8& o3) {
    float f[8] = {va.x, va.y, va.z, va.w, vb.x, vb.y, vb.z, vb.w};
    union U { bhalf8 v; unsigned int u[4]; } u1, u2, u3;
#pragma unroll
    for (int t = 0; t < 4; t++) {
        float a = f[2 * t], b = f[2 * t + 1];
        unsigned int ua = __float_as_uint(a), ub = __float_as_uint(b);
        float da = a - __uint_as_float(ua & 0xFFFF0000u);
        float db = b - __uint_as_float(ub & 0xFFFF0000u);
        unsigned int uda = __float_as_uint(da), udb = __float_as_uint(db);
        float da2 = da - __uint_as_float(uda & 0xFFFF0000u);
        float db2 = db - __uint_as_float(udb & 0xFFFF0000u);
        u1.u[t] = (ua >> 16) | (ub & 0xFFFF0000u);
        u2.u[t] = (uda >> 16) | (udb & 0xFFFF0000u);
        u3.u[t] = (__float_as_uint(da2) >> 16) | (__float_as_uint(db2) & 0xFFFF0000u);
    }
    o1 = u1.v; o2 = u2.v; o3 = u3.v;
}

// ---- pre-kernel: split W into 3 bf16 planes in coalesced B-fragment layout ----
__global__ __launch_bounds__(64) void wsplit_kernel(const float* __restrict__ W,
                                                    char* __restrict__ wq,
                                                    float* __restrict__ wsf) {
    if (blockIdx.x < 3) wsf[blockIdx.x * 64 + threadIdx.x] = 0.f;   // zero accum[0,192)
    int idx8 = (blockIdx.x * 64 + threadIdx.x) * 8;   // 16384 threads x 8 elems
    int e = idx8 >> 11;
    int k0 = idx8 & 2047;                // octet-aligned k
    int c = k0 >> 6, ks = (k0 >> 4) & 3, half = (k0 >> 3) & 1;
    int g = e >> 5, l = (e & 31) + 32 * half;
    const float4* wp = (const float4*)(W + (size_t)e * HID + k0);
    float4 v0 = wp[0], v1 = wp[1];
    float f[8] = {v0.x, v0.y, v0.z, v0.w, v1.x, v1.y, v1.z, v1.w};
    unsigned int p1[4], p2[4], p3[4];
#pragma unroll
    for (int t = 0; t < 4; t++) {
        unsigned short a1, a2, a3, b1, b2, b3;
        split3(f[2 * t], a1, a2, a3);
        split3(f[2 * t + 1], b1, b2, b3);
        p1[t] = (unsigned int)a1 | ((unsigned int)b1 << 16);
        p2[t] = (unsigned int)a2 | ((unsigned int)b2 << 16);
        p3[t] = (unsigned int)a3 | ((unsigned int)b3 << 16);
    }
    char* base = wq + (size_t)(((c * 4 + ks) * 3 + 0) * 2 + g) * 1024 + l * 16;
    *(uint4*)(base)        = make_uint4(p1[0], p1[1], p1[2], p1[3]);   // plane 1
    *(uint4*)(base + 2048) = make_uint4(p2[0], p2[1], p2[2], p2[3]);   // plane 2
    *(uint4*)(base + 4096) = make_uint4(p3[0], p3[1], p3[2], p3[3]);   // plane 3
}

__global__ __launch_bounds__(NTHREADS, 2) void router_main(
    const float* __restrict__ x, const char* __restrict__ wq,
    float* __restrict__ out, float* __restrict__ wsf)
{
    __shared__ float slab[TM * 68];    // 17.4 KB accumulated logits
    __shared__ float scount[NEXP];
    __shared__ float sprob[NEXP];
    __shared__ int slast;

    const int tid = threadIdx.x;
    const int w = tid >> 6;        // kphase / wave id
    const int lane = tid & 63;
    const int r = lane & 31;       // A row (token) / B expert within group
    const int h = lane >> 5;       // k-octet half
    const int n0 = blockIdx.x * TM;

    // zero logit accumulator + stats
    for (int i = tid; i < TM * 68; i += NTHREADS) slab[i] = 0.f;
    if (tid < NEXP) { scount[tid] = 0.f; sprob[tid] = 0.f; }
    __syncthreads();

    const float* xrow0 = x + (size_t)(n0 + r) * HID + h * 8;        // tile 0: rows n0..n0+31
    const float* xrow1 = x + (size_t)(n0 + 32 + r) * HID + h * 8;   // tile 1: rows n0+32..n0+63

    f32x16 a00, a01, a10, a11;   // [tile][expert-group]
#pragma unroll
    for (int i = 0; i < 16; i++) { a00[i] = 0.f; a01[i] = 0.f; a10[i] = 0.f; a11[i] = 0.f; }

    // ---- free-running K-loop: compiler-scheduled, no barriers ----
#pragma unroll 1
    for (int i = 0; i < CPW; ++i) {
        const int c = w * CPW + i;
        const float* xc0 = xrow0 + c * 64;
        const float* xc1 = xrow1 + c * 64;
        // batch all 16 x-loads for this chunk (HBM-latency ones) up front
        float4 p0a[4], p0b[4], p1a[4], p1b[4];
#pragma unroll
        for (int ks = 0; ks < 4; ks++) {
            p0a[ks] = *(const float4*)(xc0 + ks * 16);
            p0b[ks] = *(const float4*)(xc0 + ks * 16 + 4);
            p1a[ks] = *(const float4*)(xc1 + ks * 16);
            p1b[ks] = *(const float4*)(xc1 + ks * 16 + 4);
        }
        const char* wc = wq + (size_t)c * CHUNK_B + lane * 16;
#pragma unroll
        for (int ks = 0; ks < 4; ks++) {
            const char* wk = wc + ks * 6144;
            // 6 shared B-frags (3 planes x 2 expert groups), each feeds both tiles
            bhalf8 B1 = *(const bhalf8*)(wk);
            bhalf8 B2 = *(const bhalf8*)(wk + 2048);
            bhalf8 B3 = *(const bhalf8*)(wk + 4096);
            bhalf8 C1 = *(const bhalf8*)(wk + 1024);
            bhalf8 C2 = *(const bhalf8*)(wk + 2048 + 1024);
            bhalf8 C3 = *(const bhalf8*)(wk + 4096 + 1024);
            {
                bhalf8 A1, A2, A3;
                xsplit(p0a[ks], p0b[ks], A1, A2, A3);
                a00 = __builtin_amdgcn_mfma_f32_32x32x16_bf16(A1, B1, a00, 0, 0, 0);
                a01 = __builtin_amdgcn_mfma_f32_32x32x16_bf16(A1, C1, a01, 0, 0, 0);
                a00 = __builtin_amdgcn_mfma_f32_32x32x16_bf16(A1, B2, a00, 0, 0, 0);
                a01 = __builtin_amdgcn_mfma_f32_32x32x16_bf16(A1, C2, a01, 0, 0, 0);
                a00 = __builtin_amdgcn_mfma_f32_32x32x16_bf16(A2, B1, a00, 0, 0, 0);
                a01 = __builtin_amdgcn_mfma_f32_32x32x16_bf16(A2, C1, a01, 0, 0, 0);
                a00 = __builtin_amdgcn_mfma_f32_32x32x16_bf16(A1, B3, a00, 0, 0, 0);
                a01 = __builtin_amdgcn_mfma_f32_32x32x16_bf16(A1, C3, a01, 0, 0, 0);
                a00 = __builtin_amdgcn_mfma_f32_32x32x16_bf16(A2, B2, a00, 0, 0, 0);
                a01 = __builtin_amdgcn_mfma_f32_32x32x16_bf16(A2, C2, a01, 0, 0, 0);
                a00 = __builtin_amdgcn_mfma_f32_32x32x16_bf16(A3, B1, a00, 0, 0, 0);
                a01 = __builtin_amdgcn_mfma_f32_32x32x16_bf16(A3, C1, a01, 0, 0, 0);
            }
            {
                bhalf8 D1, D2, D3;
                xsplit(p1a[ks], p1b[ks], D1, D2, D3);
                a10 = __builtin_amdgcn_mfma_f32_32x32x16_bf16(D1, B1, a10, 0, 0, 0);
                a11 = __builtin_amdgcn_mfma_f32_32x32x16_bf16(D1, C1, a11, 0, 0, 0);
                a10 = __builtin_amdgcn_mfma_f32_32x32x16_bf16(D1, B2, a10, 0, 0, 0);
                a11 = __builtin_amdgcn_mfma_f32_32x32x16_bf16(D1, C2, a11, 0, 0, 0);
                a10 = __builtin_amdgcn_mfma_f32_32x32x16_bf16(D2, B1, a10, 0, 0, 0);
                a11 = __builtin_amdgcn_mfma_f32_32x32x16_bf16(D2, C1, a11, 0, 0, 0);
                a10 = __builtin_amdgcn_mfma_f32_32x32x16_bf16(D1, B3, a10, 0, 0, 0);
                a11 = __builtin_amdgcn_mfma_f32_32x32x16_bf16(D1, C3, a11, 0, 0, 0);
                a10 = __builtin_amdgcn_mfma_f32_32x32x16_bf16(D2, B2, a10, 0, 0, 0);
                a11 = __builtin_amdgcn_mfma_f32_32x32x16_bf16(D2, C2, a11, 0, 0, 0);
                a10 = __builtin_amdgcn_mfma_f32_32x32x16_bf16(D3, B1, a10, 0, 0, 0);
                a11 = __builtin_amdgcn_mfma_f32_32x32x16_bf16(D3, C1, a11, 0, 0, 0);
            }
        }
    }

    // ---- combine: accumulate partial tiles via LDS atomics (ds_add_f32, 2-way banks = free) ----
    // C/D 32x32 layout: col = lane&31, row = (reg&3) + 8*(reg>>2) + 4*(lane>>5)  [m74/m101]
#pragma unroll
    for (int reg = 0; reg < 16; reg++) {
        int row = (reg & 3) + 8 * (reg >> 2) + 4 * h;
        atomicAdd(&slab[row * 68 + r],             a00[reg]);
        atomicAdd(&slab[row * 68 + 32 + r],        a01[reg]);
        atomicAdd(&slab[(32 + row) * 68 + r],      a10[reg]);
        atomicAdd(&slab[(32 + row) * 68 + 32 + r], a11[reg]);
    }
    __syncthreads();

    // ---- wave-parallel epilogue: wave w handles tokens w*TPW .. w*TPW+7 ----
    const float* logits = slab;
    float pacc = 0.f;   // per-lane (expert=lane) softmax-prob sum over this wave's tokens
#pragma unroll 1
    for (int j = 0; j < TPW; j++) {
        const int t = w * TPW + j;
        const float v = logits[t * 68 + lane];
        float m1 = v, m2 = -3.4e38f;
        int i1 = lane, i2 = 0;
#pragma unroll
        for (int off = 32; off > 0; off >>= 1) {
            float om1 = __shfl_xor(m1, off);
            int   oi1 = __shfl_xor(i1, off);
            float om2 = __shfl_xor(m2, off);
            int   oi2 = __shfl_xor(i2, off);
            if (om1 > m1 || (om1 == m1 && oi1 < i1)) {
                if (m1 > om2 || (m1 == om2 && i1 < oi2)) { m2 = m1; i2 = i1; }
                else { m2 = om2; i2 = oi2; }
                m1 = om1; i1 = oi1;
            } else {
                if (om1 > m2 || (om1 == m2 && oi1 < i2)) { m2 = om1; i2 = oi1; }
            }
        }
        float p = __expf(v - m1);
        float Z = p;
#pragma unroll
        for (int off = 32; off > 0; off >>= 1) Z += __shfl_xor(Z, off);
        float invZ = 1.f / Z;
        pacc += p * invZ;
        if (lane == 0) {
            float p1 = invZ;
            float p2 = __expf(m2 - m1) * invZ;
            float denom = p1 + p2 + 1e-6f;
            int n = n0 + t;
            out[2 * n + 0] = p1 / denom;
            out[2 * n + 1] = p2 / denom;
            out[OUT_IDX_OFF + 2 * n + 0] = (float)i1;
            out[OUT_IDX_OFF + 2 * n + 1] = (float)i2;
            atomicAdd(&scount[i1], 1.f);
            atomicAdd(&scount[i2], 1.f);
        }
    }
    atomicAdd(&sprob[lane], pacc);
    __syncthreads();

    if (tid < NEXP) {
        atomicAdd(&wsf[tid], sprob[tid]);
        atomicAdd(&wsf[NEXP + tid], scount[tid]);
    }

    // ---- last block computes aux loss + counts (fused router_finish) ----
    __threadfence();
    if (tid == 0) {
        unsigned prev = __hip_atomic_fetch_add((unsigned int*)(wsf + 2 * NEXP), 1u,
                                               __ATOMIC_ACQ_REL, __HIP_MEMORY_SCOPE_AGENT);
        slast = (prev == NBLK - 1) ? 1 : 0;
    }
    __syncthreads();
    if (slast && tid < NEXP) {
        const int e = tid;
        const float invN = 1.f / (float)NTOK;
        float ps = __hip_atomic_load(wsf + e, __ATOMIC_RELAXED, __HIP_MEMORY_SCOPE_AGENT);
        float cs = __hip_atomic_load(wsf + NEXP + e, __ATOMIC_RELAXED, __HIP_MEMORY_SCOPE_AGENT);
        out[OUT_CNT_OFF + e] = cs;
        float p = ps * invN;
        float a = cs * invN;
        float v = p * p + a * a;
#pragma unroll
        for (int off = 32; off > 0; off >>= 1)
            v += __shfl_down(v, off);
        if (e == 0) out[OUT_AUX_OFF] = v * (float)NEXP;
    }
}

extern "C" void kernel_launch(void* const* d_in, const int* in_sizes, int n_in,
                              void* d_out, int out_size, void* d_ws, size_t ws_size,
                              hipStream_t stream)
{
    const float* x = (const float*)d_in[0];   // [4,4096,2048] f32
    const float* W = (const float*)d_in[1];   // [64,2048] f32
    float* out = (float*)d_out;
    float* wsf = (float*)d_ws;
    char* wq = (char*)d_ws + WS_W_OFF;        // W planes: 32 chunks x 24576 B = 768 KB

    wsplit_kernel<<<256, 64, 0, stream>>>(W, wq, wsf);   // also zeros accum+counter
    router_main<<<NBLK, NTHREADS, 0, stream>>>(x, wq, out, wsf);
}